// Round 3
// baseline (790.150 us; speedup 1.0000x reference)
//
#include <hip/hip_runtime.h>
#include <hip/hip_bf16.h>
#include <math.h>

// Starcoder2 attention R7:
//  - attn in f16: single-MFMA QK^T (f16 rel err 2^-11; logit err ~7e-4, an
//    order below bf16 PV/GEMM rounding), f16 PV (more accurate than bf16).
//    Kl image gone -> LDS 37 KB -> 4 blocks/CU. exp -> exp2 (scale*log2e
//    folded into Q). T13 defer-max (THR=8 log2-units, wave-uniform __any).
//    Heavy q-blocks first (q0 reversed).
//  - GEMM: BK=64 as two [128][32] sub-tiles (same verified per-sub-tile
//    layout as m97 BK=32) -> half the vmcnt(0)+barrier drains per K.
//  - prep_kv: RoPE(K)+f16 K image, f16 V-transposed image (8 KB each/tile).
// T=2048, HID=4608, H=36, KV=4, D=128, window=1024.

#define T_SEQ   2048
#define HIDDEN  4608
#define NHEAD   36
#define NKVH    4
#define HEADDIM 128
#define GQA_G   9
#define NQKV    5632
#define KOFF    4608
#define VOFF    5120
#define NEG_BIG -1e30f
#define BQ 64
#define BS 32
#define NTILE   64            // T_SEQ / BS
#define PSTR 40

typedef short    bf16x8 __attribute__((ext_vector_type(8)));
typedef _Float16 f16x8  __attribute__((ext_vector_type(8)));
typedef float    f32x4  __attribute__((ext_vector_type(4)));

// pack 8 fp32 -> 8 bf16 (RNE)
__device__ inline bf16x8 pack8(float4 u, float4 v) {
    union { bf16x8 v8; __hip_bfloat162 h[4]; } r;
    r.h[0] = __float22bfloat162_rn(make_float2(u.x, u.y));
    r.h[1] = __float22bfloat162_rn(make_float2(u.z, u.w));
    r.h[2] = __float22bfloat162_rn(make_float2(v.x, v.y));
    r.h[3] = __float22bfloat162_rn(make_float2(v.z, v.w));
    return r.v8;
}

// async global->LDS, 16 B per lane. LDS dest wave-uniform; lane l lands at
// ldsbase + l*16; global source address is per-lane.
typedef const __attribute__((address_space(1))) int* gas_ptr;
typedef __attribute__((address_space(3))) int*       las_ptr;
__device__ __forceinline__ void gload_lds16(const void* g, void* l) {
    __builtin_amdgcn_global_load_lds((gas_ptr)g, (las_ptr)l, 16, 0, 0);
}

// ---------------------------------------------------------------------------
// fp32 -> bf16 conversion (memory-bound, vectorized 8 elems/thread/iter)
// ---------------------------------------------------------------------------
__global__ __launch_bounds__(256)
void cvt_bf16_kernel(const float* __restrict__ in, __hip_bfloat16* __restrict__ out,
                     int n8)
{
    for (int i = blockIdx.x * 256 + threadIdx.x; i < n8; i += gridDim.x * 256) {
        const float4 a = *(const float4*)(in + (size_t)i * 8);
        const float4 b = *(const float4*)(in + (size_t)i * 8 + 4);
        *(bf16x8*)(out + (size_t)i * 8) = pack8(a, b);
    }
}

// ---------------------------------------------------------------------------
// GEMM: C[M,N](fp32) = A[M,K](bf16) @ B[N,K](bf16)^T + bias
// 128x128 tile, BK=64 as two [128][32] sub-tiles, 4 waves,
// global_load_lds staging (m97 structure, halved barrier count).
// ---------------------------------------------------------------------------
__global__ __launch_bounds__(256)
void gemm_bf16bt_kernel(const __hip_bfloat16* __restrict__ A,
                        const __hip_bfloat16* __restrict__ B,
                        const float* __restrict__ bias,
                        float* __restrict__ C, int N, int K)
{
    __shared__ short As[2][128 * 32];   // [kk-half][row][32], 8 KB each
    __shared__ short Bs[2][128 * 32];

    const int tid  = threadIdx.x;
    const int lane = tid & 63;
    const int wave = tid >> 6;
    const int row0 = blockIdx.y * 128;
    const int col0 = blockIdx.x * 128;
    const int wr   = (wave >> 1) * 64;
    const int wc   = (wave & 1) * 64;
    const int fr   = lane & 15;
    const int fk   = (lane >> 4) * 8;

    // staging: 1 KB chunk = 16 rows x 64 B; lane l -> row +(l>>2), col (l&3)*8
    const int srow = lane >> 2;
    const int scol = (lane & 3) * 8;

    const __hip_bfloat16* Ag = A + (size_t)(row0 + wave * 32 + srow) * K + scol;
    const __hip_bfloat16* Bg = B + (size_t)(col0 + wave * 32 + srow) * K + scol;

    f32x4 acc[4][4];
    #pragma unroll
    for (int i = 0; i < 4; ++i)
        #pragma unroll
        for (int j = 0; j < 4; ++j)
            #pragma unroll
            for (int r = 0; r < 4; ++r) acc[i][j][r] = 0.0f;

    for (int k0 = 0; k0 < K; k0 += 64) {
        __syncthreads();
        #pragma unroll
        for (int kk = 0; kk < 2; ++kk)
            #pragma unroll
            for (int i = 0; i < 2; ++i) {
                gload_lds16(Ag + k0 + kk * 32 + (size_t)(i * 16) * K,
                            &As[kk][(wave * 32 + i * 16) * 32]);
                gload_lds16(Bg + k0 + kk * 32 + (size_t)(i * 16) * K,
                            &Bs[kk][(wave * 32 + i * 16) * 32]);
            }
        __syncthreads();

        #pragma unroll
        for (int kk = 0; kk < 2; ++kk) {
            bf16x8 af[4], bfr[4];
            #pragma unroll
            for (int i = 0; i < 4; ++i)
                af[i] = *(const bf16x8*)&As[kk][(wr + i * 16 + fr) * 32 + fk];
            #pragma unroll
            for (int j = 0; j < 4; ++j)
                bfr[j] = *(const bf16x8*)&Bs[kk][(wc + j * 16 + fr) * 32 + fk];

            #pragma unroll
            for (int i = 0; i < 4; ++i)
                #pragma unroll
                for (int j = 0; j < 4; ++j)
                    acc[i][j] = __builtin_amdgcn_mfma_f32_16x16x32_bf16(
                        af[i], bfr[j], acc[i][j], 0, 0, 0);
        }
    }

    const int quad = lane >> 4;
    #pragma unroll
    for (int j = 0; j < 4; ++j) {
        const int col = col0 + wc + j * 16 + fr;
        const float bv = bias[col];
        #pragma unroll
        for (int i = 0; i < 4; ++i) {
            const int rowb = row0 + wr + i * 16 + quad * 4;
            #pragma unroll
            for (int r = 0; r < 4; ++r)
                C[(size_t)(rowb + r) * N + col] = acc[i][j][r] + bv;
        }
    }
}

// ---------------------------------------------------------------------------
// prep_kv: per (tile, kvh) build two 8KB f16 LDS images:
//   K image [gd=d/8][s][j]: RoPE'd K, f16      (gd 0..15, s 0..31, j=d%8)
//   V image [q=s/8][d][j] : V transposed, f16  (q 0..3, d 0..127, j=s%8)
// grid (NTILE, NKVH) x 256 threads.
// ---------------------------------------------------------------------------
__global__ __launch_bounds__(256)
void prep_kv_kernel(const int* __restrict__ positions,
                    const float* __restrict__ qkv,
                    _Float16* __restrict__ Kt,
                    _Float16* __restrict__ Vt)
{
    const int tile = blockIdx.x;
    const int kvh  = blockIdx.y;
    const int t    = threadIdx.x;
    const size_t ib = ((size_t)kvh * NTILE + tile) * 4096;

    // ---- K: thread -> row s = t>>3, d-halfpair base j8 = (t&7)*8
    {
        const int s   = t >> 3;
        const int j8  = (t & 7) * 8;
        const int row = tile * BS + s;
        const float* kp = qkv + (size_t)row * NQKV + KOFF + kvh * HEADDIM;
        float x1[8], x2[8];
        *(float4*)&x1[0] = *(const float4*)(kp + j8);
        *(float4*)&x1[4] = *(const float4*)(kp + j8 + 4);
        *(float4*)&x2[0] = *(const float4*)(kp + 64 + j8);
        *(float4*)&x2[4] = *(const float4*)(kp + 64 + j8 + 4);
        const float pos = (float)positions[row];
        f16x8 H1, H2;
        #pragma unroll
        for (int j = 0; j < 8; ++j) {
            const int d = j8 + j;
            const float inv_freq = __expf(-(float)d * (11.512925465f / 64.0f));
            float sn, cs;
            sincosf(pos * inv_freq, &sn, &cs);
            H1[j] = (_Float16)(x1[j] * cs - x2[j] * sn);
            H2[j] = (_Float16)(x2[j] * cs + x1[j] * sn);
        }
        const int gd1 = (t & 7);       // d in [0,64)
        const int gd2 = gd1 + 8;       // d+64
        *(f16x8*)&Kt[ib + gd1 * 256 + s * 8] = H1;
        *(f16x8*)&Kt[ib + gd2 * 256 + s * 8] = H2;
    }

    // ---- V: thread -> q = t>>6, d-pair d0 = (t&63)*2
    {
        const int q  = t >> 6;
        const int d0 = (t & 63) * 2;
        const float* vp = qkv + (size_t)(tile * BS + q * 8) * NQKV + VOFF
                        + kvh * HEADDIM + d0;
        f16x8 V0, V1;
        #pragma unroll
        for (int j = 0; j < 8; ++j) {
            const float2 vv = *(const float2*)(vp + (size_t)j * NQKV);
            V0[j] = (_Float16)vv.x;
            V1[j] = (_Float16)vv.y;
        }
        *(f16x8*)&Vt[ib + q * 1024 + d0 * 8]       = V0;
        *(f16x8*)&Vt[ib + q * 1024 + (d0 + 1) * 8] = V1;
    }
}

// ---------------------------------------------------------------------------
// MFMA flash attention (windowed causal GQA), R7: all-f16 math.
// K/V staged from precomputed tile images via global_load_lds, 2-phase
// double buffer. RoPE(Q) in-register, scale*log2e folded -> exp2 softmax,
// T13 defer-max. Output bf16. LDS 37 KB -> 4 blocks/CU.
// ---------------------------------------------------------------------------
__global__ __launch_bounds__(256)
void attn_kernel(const float* __restrict__ qkv,
                 const int* __restrict__ positions,
                 const _Float16* __restrict__ Kt,
                 const _Float16* __restrict__ Vt,
                 __hip_bfloat16* __restrict__ out,
                 const int* __restrict__ windowp)
{
    __shared__ _Float16 KS[2][4096];                // 16 KB
    __shared__ _Float16 VS[2][4096];                // 16 KB
    __shared__ _Float16 Ps[4][16 * PSTR];           // 5 KB   (total 37888 B)

    const int h    = blockIdx.x;
    const int q0   = (T_SEQ / BQ - 1 - blockIdx.y) * BQ;   // heavy blocks first
    const int kvh  = h / GQA_G;
    const int tid  = threadIdx.x;
    const int lane = tid & 63;
    const int wave = tid >> 6;
    const int l15  = lane & 15;
    const int quad = lane >> 4;
    const int window = *windowp;
    // 1/sqrt(128) * log2(e): softmax done in exp2 domain
    const float scale = 0.088388347648318447f * 1.4426950408889634f;

    // ---- Q load + in-register RoPE + scale + f16 A-frags; A row m = l15
    f16x8 qf[4];
    {
        const int qrow = q0 + wave * 16 + l15;
        const float* qp = qkv + (size_t)qrow * NQKV + h * HEADDIM + quad * 8;
        float qv[32];                         // [ks*8+j] = Q[d = ks*32+quad*8+j]
        #pragma unroll
        for (int ks = 0; ks < 4; ++ks) {
            *(float4*)&qv[ks * 8]     = *(const float4*)(qp + ks * 32);
            *(float4*)&qv[ks * 8 + 4] = *(const float4*)(qp + ks * 32 + 4);
        }
        const float pos = (float)positions[qrow];
        #pragma unroll
        for (int p = 0; p < 2; ++p)
            #pragma unroll
            for (int j = 0; j < 8; ++j) {
                const int d = p * 32 + quad * 8 + j;       // < 64
                const float inv_freq = __expf(-(float)d * (11.512925465f / 64.0f));
                float sn, cs;
                sincosf(pos * inv_freq, &sn, &cs);
                const float x1 = qv[p * 8 + j];            // d
                const float x2 = qv[(p + 2) * 8 + j];      // d+64
                qv[p * 8 + j]       = x1 * cs - x2 * sn;
                qv[(p + 2) * 8 + j] = x2 * cs + x1 * sn;
            }
        #pragma unroll
        for (int ks = 0; ks < 4; ++ks)
            #pragma unroll
            for (int j = 0; j < 8; ++j)
                qf[ks][j] = (_Float16)(qv[ks * 8 + j] * scale);
    }

    f32x4 o[8];
    #pragma unroll
    for (int c = 0; c < 8; ++c)
        #pragma unroll
        for (int r = 0; r < 4; ++r) o[c][r] = 0.0f;
    float mrun[4], lrun[4];
    #pragma unroll
    for (int r = 0; r < 4; ++r) { mrun[r] = NEG_BIG; lrun[r] = 0.0f; }

    int s_lo = q0 - window + 1;
    if (s_lo < 0) s_lo = 0;
    s_lo &= ~(BS - 1);
    const int tile0  = s_lo >> 5;
    const int ntiles = ((q0 + BQ) - s_lo) >> 5;

    const _Float16* gK = Kt + ((size_t)kvh * NTILE) * 4096;
    const _Float16* gV = Vt + ((size_t)kvh * NTILE) * 4096;

    _Float16* Psw = &Ps[wave][0];

    // per-wave stage of one tile's two 8KB images (2 x 1KB chunks each)
    auto STAGE = [&](int buf, int tile) {
        const size_t toff = (size_t)tile * 4096;
        #pragma unroll
        for (int i = 0; i < 2; ++i) {
            const int o = (wave * 2 + i) * 512;          // halves
            gload_lds16(gK + toff + o + lane * 8, &KS[buf][o]);
            gload_lds16(gV + toff + o + lane * 8, &VS[buf][o]);
        }
    };

    STAGE(0, tile0);
    __syncthreads();                       // drains vmcnt -> buf0 ready
    int cur = 0;

    for (int it = 0; it < ntiles; ++it) {
        const int st = s_lo + it * BS;
        if (it + 1 < ntiles) STAGE(cur ^ 1, tile0 + it + 1);   // prefetch

        // ---- S = Q K^T  (two 16x16 subtiles over s), log2-units
        f32x4 acc0, acc1;
        #pragma unroll
        for (int r = 0; r < 4; ++r) { acc0[r] = 0.0f; acc1[r] = 0.0f; }
        #pragma unroll
        for (int ks = 0; ks < 4; ++ks) {
            const int g = (ks * 4 + quad) * 256;         // granule gd = d/8
            const f16x8 b0 = *(const f16x8*)&KS[cur][g + l15 * 8];
            const f16x8 b1 = *(const f16x8*)&KS[cur][g + (16 + l15) * 8];
            acc0 = __builtin_amdgcn_mfma_f32_16x16x32_f16(qf[ks], b0, acc0, 0, 0, 0);
            acc1 = __builtin_amdgcn_mfma_f32_16x16x32_f16(qf[ks], b1, acc1, 0, 0, 0);
        }

        // ---- mask + online softmax (exp2 domain, defer-max THR=8)
        const int qb  = q0 + wave * 16 + quad * 4;
        const int s0g = st + l15;
        const int s1g = st + 16 + l15;
        #pragma unroll
        for (int r = 0; r < 4; ++r) {
            const int q = qb + r;
            const bool v0 = (s0g <= q) && (s0g > q - window);
            const bool v1 = (s1g <= q) && (s1g > q - window);
            float a = v0 ? acc0[r] : NEG_BIG;
            float b = v1 ? acc1[r] : NEG_BIG;
            float mx = fmaxf(a, b);
            mx = fmaxf(mx, __shfl_xor(mx, 1));
            mx = fmaxf(mx, __shfl_xor(mx, 2));
            mx = fmaxf(mx, __shfl_xor(mx, 4));
            mx = fmaxf(mx, __shfl_xor(mx, 8));
            if (__any(mx > mrun[r] + 8.0f)) {            // wave-uniform
                const float mnew  = fmaxf(mrun[r], mx);
                const float alpha = __builtin_amdgcn_exp2f(mrun[r] - mnew);
                mrun[r] = mnew;
                lrun[r] *= alpha;
                #pragma unroll
                for (int c = 0; c < 8; ++c) o[c][r] *= alpha;
            }
            const float e0 = v0 ? __builtin_amdgcn_exp2f(acc0[r] - mrun[r]) : 0.0f;
            const float e1 = v1 ? __builtin_amdgcn_exp2f(acc1[r] - mrun[r]) : 0.0f;
            const _Float16 p0 = (_Float16)e0;
            const _Float16 p1 = (_Float16)e1;
            Psw[(quad * 4 + r) * PSTR + l15]      = p0;
            Psw[(quad * 4 + r) * PSTR + 16 + l15] = p1;
            float sum = (float)p0 + (float)p1;
            sum += __shfl_xor(sum, 1);
            sum += __shfl_xor(sum, 2);
            sum += __shfl_xor(sum, 4);
            sum += __shfl_xor(sum, 8);
            lrun[r] += sum;
        }

        // ---- PV: A = P (A-layout from per-wave LDS), B = V image rows
        const f16x8 pa = *(const f16x8*)&Psw[l15 * PSTR + quad * 8];
        #pragma unroll
        for (int c = 0; c < 8; ++c) {
            const f16x8 vb = *(const f16x8*)&VS[cur][quad * 1024 + (16 * c + l15) * 8];
            o[c] = __builtin_amdgcn_mfma_f32_16x16x32_f16(pa, vb, o[c], 0, 0, 0);
        }

        __syncthreads();    // drains vmcnt (prefetch landed) + buf reuse fence
        cur ^= 1;
    }

    // ---- epilogue: normalize, write bf16 out[q][h*128 + d]
    #pragma unroll
    for (int r = 0; r < 4; ++r) {
        const float inv = 1.0f / lrun[r];   // diagonal always valid
        __hip_bfloat16* op = out
                  + (size_t)(q0 + wave * 16 + quad * 4 + r) * (NHEAD * HEADDIM)
                  + h * HEADDIM + l15;
        #pragma unroll
        for (int c = 0; c < 8; ++c) op[16 * c] = __float2bfloat16(o[c][r] * inv);
    }
}

// ---------------------------------------------------------------------------
extern "C" void kernel_launch(void* const* d_in, const int* in_sizes, int n_in,
                              void* d_out, int out_size, void* d_ws, size_t ws_size,
                              hipStream_t stream)
{
    const int*   positions = (const int*)d_in[0];
    const float* hidden    = (const float*)d_in[1];
    const float* wqkv      = (const float*)d_in[2];
    const float* bqkv      = (const float*)d_in[3];
    const float* wo        = (const float*)d_in[4];
    const float* bo        = (const float*)d_in[5];
    const int*   windowp   = (const int*)d_in[6];
    float* outp = (float*)d_out;

    // ws layout:
    //   qkv   fp32 [T,5632]      46.1 MB
    //   hbf   bf16 [T,4608]      18.9 MB
    //   wqbf  bf16 [5632,4608]   51.9 MB
    //   wobf  bf16 [4608,4608]   42.5 MB
    //   abf   bf16 [T,4608]      18.9 MB
    //   Kt/Vt f16 tile images    2 x 2.0 MB
    float* qkv = (float*)d_ws;
    __hip_bfloat16* hbf  = (__hip_bfloat16*)(qkv + (size_t)T_SEQ * NQKV);
    __hip_bfloat16* wqbf = hbf  + (size_t)T_SEQ * HIDDEN;
    __hip_bfloat16* wobf = wqbf + (size_t)NQKV * HIDDEN;
    __hip_bfloat16* abf  = wobf + (size_t)HIDDEN * HIDDEN;
    _Float16*       Kt   = (_Float16*)(abf + (size_t)T_SEQ * HIDDEN);
    _Float16*       Vt   = Kt + (size_t)NKVH * NTILE * 4096;

    cvt_bf16_kernel<<<1024, 256, 0, stream>>>(hidden, hbf, T_SEQ * HIDDEN / 8);
    cvt_bf16_kernel<<<2048, 256, 0, stream>>>(wqkv, wqbf, NQKV * HIDDEN / 8);
    cvt_bf16_kernel<<<2048, 256, 0, stream>>>(wo, wobf, HIDDEN * HIDDEN / 8);

    gemm_bf16bt_kernel<<<dim3(NQKV / 128, T_SEQ / 128), 256, 0, stream>>>(
        hbf, wqbf, bqkv, qkv, NQKV, HIDDEN);

    prep_kv_kernel<<<dim3(NTILE, NKVH), 256, 0, stream>>>(
        positions, qkv, Kt, Vt);

    attn_kernel<<<dim3(NHEAD, T_SEQ / BQ), 256, 0, stream>>>(
        qkv, positions, Kt, Vt, abf, windowp);

    gemm_bf16bt_kernel<<<dim3(HIDDEN / 128, T_SEQ / 128), 256, 0, stream>>>(
        abf, wobf, bo, outp, HIDDEN, HIDDEN);
}

// Round 5
// 627.309 us; speedup vs baseline: 1.2596x; 1.2596x over previous
//
#include <hip/hip_runtime.h>
#include <hip/hip_bf16.h>
#include <math.h>

// Starcoder2 attention R8b (identical to R8; R8's bench was an infra flake):
//  - GEMM: BK=32 (R5-verified layout) + LDS DOUBLE BUFFER, T3 minimum
//    2-phase schedule: STAGE(t+1) -> compute(t) -> one vmcnt(0)+barrier per
//    K-step (same barrier pattern as the verified attn loop). Race audit:
//    prefetch at iter k overwrites tile k-1's buffer whose reads finished
//    before the iter-(k-1) barrier; __syncthreads drains vmcnt so the
//    prefetch has landed before iter k+1's ds_reads.
//  - attn/prep_kv/cvt: unchanged from R7 (f16 QK+PV, exp2 softmax,
//    defer-max, image-staged K/V, in-register RoPE(Q)).
// T=2048, HID=4608, H=36, KV=4, D=128, window=1024.

#define T_SEQ   2048
#define HIDDEN  4608
#define NHEAD   36
#define NKVH    4
#define HEADDIM 128
#define GQA_G   9
#define NQKV    5632
#define KOFF    4608
#define VOFF    5120
#define NEG_BIG -1e30f
#define BQ 64
#define BS 32
#define NTILE   64            // T_SEQ / BS
#define PSTR 40

typedef short    bf16x8 __attribute__((ext_vector_type(8)));
typedef _Float16 f16x8  __attribute__((ext_vector_type(8)));
typedef float    f32x4  __attribute__((ext_vector_type(4)));

// pack 8 fp32 -> 8 bf16 (RNE)
__device__ inline bf16x8 pack8(float4 u, float4 v) {
    union { bf16x8 v8; __hip_bfloat162 h[4]; } r;
    r.h[0] = __float22bfloat162_rn(make_float2(u.x, u.y));
    r.h[1] = __float22bfloat162_rn(make_float2(u.z, u.w));
    r.h[2] = __float22bfloat162_rn(make_float2(v.x, v.y));
    r.h[3] = __float22bfloat162_rn(make_float2(v.z, v.w));
    return r.v8;
}

// async global->LDS, 16 B per lane. LDS dest wave-uniform; lane l lands at
// ldsbase + l*16; global source address is per-lane.
typedef const __attribute__((address_space(1))) int* gas_ptr;
typedef __attribute__((address_space(3))) int*       las_ptr;
__device__ __forceinline__ void gload_lds16(const void* g, void* l) {
    __builtin_amdgcn_global_load_lds((gas_ptr)g, (las_ptr)l, 16, 0, 0);
}

// ---------------------------------------------------------------------------
// fp32 -> bf16 conversion (memory-bound, vectorized 8 elems/thread/iter)
// ---------------------------------------------------------------------------
__global__ __launch_bounds__(256)
void cvt_bf16_kernel(const float* __restrict__ in, __hip_bfloat16* __restrict__ out,
                     int n8)
{
    for (int i = blockIdx.x * 256 + threadIdx.x; i < n8; i += gridDim.x * 256) {
        const float4 a = *(const float4*)(in + (size_t)i * 8);
        const float4 b = *(const float4*)(in + (size_t)i * 8 + 4);
        *(bf16x8*)(out + (size_t)i * 8) = pack8(a, b);
    }
}

// ---------------------------------------------------------------------------
// GEMM: C[M,N](fp32) = A[M,K](bf16) @ B[N,K](bf16)^T + bias
// 128x128 tile, BK=32, 4 waves, global_load_lds staging, double-buffered
// 2-phase: STAGE(next) || compute(cur), one vmcnt(0)+barrier per K-step.
// ---------------------------------------------------------------------------
__global__ __launch_bounds__(256)
void gemm_bf16bt_kernel(const __hip_bfloat16* __restrict__ A,
                        const __hip_bfloat16* __restrict__ B,
                        const float* __restrict__ bias,
                        float* __restrict__ C, int N, int K)
{
    __shared__ short As[2][128 * 32];   // 8 KB each, row-major [row][k]
    __shared__ short Bs[2][128 * 32];

    const int tid  = threadIdx.x;
    const int lane = tid & 63;
    const int wave = tid >> 6;
    const int row0 = blockIdx.y * 128;
    const int col0 = blockIdx.x * 128;
    const int wr   = (wave >> 1) * 64;
    const int wc   = (wave & 1) * 64;
    const int fr   = lane & 15;
    const int fk   = (lane >> 4) * 8;

    // staging: 1 KB chunk = 16 rows x 64 B; lane l -> row +(l>>2), col (l&3)*8
    const int srow = lane >> 2;
    const int scol = (lane & 3) * 8;

    const __hip_bfloat16* Ag0 = A + (size_t)(row0 + wave * 32 + srow) * K + scol;
    const __hip_bfloat16* Ag1 = Ag0 + (size_t)16 * K;
    const __hip_bfloat16* Bg0 = B + (size_t)(col0 + wave * 32 + srow) * K + scol;
    const __hip_bfloat16* Bg1 = Bg0 + (size_t)16 * K;

    short* Al0[2] = { &As[0][(wave * 32) * 32],      &As[1][(wave * 32) * 32] };
    short* Al1[2] = { &As[0][(wave * 32 + 16) * 32], &As[1][(wave * 32 + 16) * 32] };
    short* Bl0[2] = { &Bs[0][(wave * 32) * 32],      &Bs[1][(wave * 32) * 32] };
    short* Bl1[2] = { &Bs[0][(wave * 32 + 16) * 32], &Bs[1][(wave * 32 + 16) * 32] };

    f32x4 acc[4][4];
    #pragma unroll
    for (int i = 0; i < 4; ++i)
        #pragma unroll
        for (int j = 0; j < 4; ++j)
            #pragma unroll
            for (int r = 0; r < 4; ++r) acc[i][j][r] = 0.0f;

    // prologue: stage tile 0 into buf 0
    gload_lds16(Ag0, Al0[0]);
    gload_lds16(Ag1, Al1[0]);
    gload_lds16(Bg0, Bl0[0]);
    gload_lds16(Bg1, Bl1[0]);
    __syncthreads();                       // drains vmcnt -> buf0 ready
    int cur = 0;

    for (int k0 = 0; k0 < K; k0 += 32) {
        if (k0 + 32 < K) {                 // prefetch next K-tile
            const int kn = k0 + 32;
            const int nb = cur ^ 1;
            gload_lds16(Ag0 + kn, Al0[nb]);
            gload_lds16(Ag1 + kn, Al1[nb]);
            gload_lds16(Bg0 + kn, Bl0[nb]);
            gload_lds16(Bg1 + kn, Bl1[nb]);
        }

        bf16x8 af[4], bfr[4];
        #pragma unroll
        for (int i = 0; i < 4; ++i)
            af[i] = *(const bf16x8*)&As[cur][(wr + i * 16 + fr) * 32 + fk];
        #pragma unroll
        for (int j = 0; j < 4; ++j)
            bfr[j] = *(const bf16x8*)&Bs[cur][(wc + j * 16 + fr) * 32 + fk];

        #pragma unroll
        for (int i = 0; i < 4; ++i)
            #pragma unroll
            for (int j = 0; j < 4; ++j)
                acc[i][j] = __builtin_amdgcn_mfma_f32_16x16x32_bf16(
                    af[i], bfr[j], acc[i][j], 0, 0, 0);

        __syncthreads();   // prefetch landed (vmcnt0) + cur-buf reads done
        cur ^= 1;
    }

    const int quad = lane >> 4;
    #pragma unroll
    for (int j = 0; j < 4; ++j) {
        const int col = col0 + wc + j * 16 + fr;
        const float bv = bias[col];
        #pragma unroll
        for (int i = 0; i < 4; ++i) {
            const int rowb = row0 + wr + i * 16 + quad * 4;
            #pragma unroll
            for (int r = 0; r < 4; ++r)
                C[(size_t)(rowb + r) * N + col] = acc[i][j][r] + bv;
        }
    }
}

// ---------------------------------------------------------------------------
// prep_kv: per (tile, kvh) build two 8KB f16 LDS images:
//   K image [gd=d/8][s][j]: RoPE'd K, f16      (gd 0..15, s 0..31, j=d%8)
//   V image [q=s/8][d][j] : V transposed, f16  (q 0..3, d 0..127, j=s%8)
// grid (NTILE, NKVH) x 256 threads.
// ---------------------------------------------------------------------------
__global__ __launch_bounds__(256)
void prep_kv_kernel(const int* __restrict__ positions,
                    const float* __restrict__ qkv,
                    _Float16* __restrict__ Kt,
                    _Float16* __restrict__ Vt)
{
    const int tile = blockIdx.x;
    const int kvh  = blockIdx.y;
    const int t    = threadIdx.x;
    const size_t ib = ((size_t)kvh * NTILE + tile) * 4096;

    // ---- K: thread -> row s = t>>3, d-halfpair base j8 = (t&7)*8
    {
        const int s   = t >> 3;
        const int j8  = (t & 7) * 8;
        const int row = tile * BS + s;
        const float* kp = qkv + (size_t)row * NQKV + KOFF + kvh * HEADDIM;
        float x1[8], x2[8];
        *(float4*)&x1[0] = *(const float4*)(kp + j8);
        *(float4*)&x1[4] = *(const float4*)(kp + j8 + 4);
        *(float4*)&x2[0] = *(const float4*)(kp + 64 + j8);
        *(float4*)&x2[4] = *(const float4*)(kp + 64 + j8 + 4);
        const float pos = (float)positions[row];
        f16x8 H1, H2;
        #pragma unroll
        for (int j = 0; j < 8; ++j) {
            const int d = j8 + j;
            const float inv_freq = __expf(-(float)d * (11.512925465f / 64.0f));
            float sn, cs;
            sincosf(pos * inv_freq, &sn, &cs);
            H1[j] = (_Float16)(x1[j] * cs - x2[j] * sn);
            H2[j] = (_Float16)(x2[j] * cs + x1[j] * sn);
        }
        const int gd1 = (t & 7);       // d in [0,64)
        const int gd2 = gd1 + 8;       // d+64
        *(f16x8*)&Kt[ib + gd1 * 256 + s * 8] = H1;
        *(f16x8*)&Kt[ib + gd2 * 256 + s * 8] = H2;
    }

    // ---- V: thread -> q = t>>6, d-pair d0 = (t&63)*2
    {
        const int q  = t >> 6;
        const int d0 = (t & 63) * 2;
        const float* vp = qkv + (size_t)(tile * BS + q * 8) * NQKV + VOFF
                        + kvh * HEADDIM + d0;
        f16x8 V0, V1;
        #pragma unroll
        for (int j = 0; j < 8; ++j) {
            const float2 vv = *(const float2*)(vp + (size_t)j * NQKV);
            V0[j] = (_Float16)vv.x;
            V1[j] = (_Float16)vv.y;
        }
        *(f16x8*)&Vt[ib + q * 1024 + d0 * 8]       = V0;
        *(f16x8*)&Vt[ib + q * 1024 + (d0 + 1) * 8] = V1;
    }
}

// ---------------------------------------------------------------------------
// MFMA flash attention (windowed causal GQA), f16 math (unchanged from R7).
// ---------------------------------------------------------------------------
__global__ __launch_bounds__(256)
void attn_kernel(const float* __restrict__ qkv,
                 const int* __restrict__ positions,
                 const _Float16* __restrict__ Kt,
                 const _Float16* __restrict__ Vt,
                 __hip_bfloat16* __restrict__ out,
                 const int* __restrict__ windowp)
{
    __shared__ _Float16 KS[2][4096];                // 16 KB
    __shared__ _Float16 VS[2][4096];                // 16 KB
    __shared__ _Float16 Ps[4][16 * PSTR];           // 5 KB   (total 37888 B)

    const int h    = blockIdx.x;
    const int q0   = (T_SEQ / BQ - 1 - blockIdx.y) * BQ;   // heavy blocks first
    const int kvh  = h / GQA_G;
    const int tid  = threadIdx.x;
    const int lane = tid & 63;
    const int wave = tid >> 6;
    const int l15  = lane & 15;
    const int quad = lane >> 4;
    const int window = *windowp;
    // 1/sqrt(128) * log2(e): softmax done in exp2 domain
    const float scale = 0.088388347648318447f * 1.4426950408889634f;

    // ---- Q load + in-register RoPE + scale + f16 A-frags; A row m = l15
    f16x8 qf[4];
    {
        const int qrow = q0 + wave * 16 + l15;
        const float* qp = qkv + (size_t)qrow * NQKV + h * HEADDIM + quad * 8;
        float qv[32];                         // [ks*8+j] = Q[d = ks*32+quad*8+j]
        #pragma unroll
        for (int ks = 0; ks < 4; ++ks) {
            *(float4*)&qv[ks * 8]     = *(const float4*)(qp + ks * 32);
            *(float4*)&qv[ks * 8 + 4] = *(const float4*)(qp + ks * 32 + 4);
        }
        const float pos = (float)positions[qrow];
        #pragma unroll
        for (int p = 0; p < 2; ++p)
            #pragma unroll
            for (int j = 0; j < 8; ++j) {
                const int d = p * 32 + quad * 8 + j;       // < 64
                const float inv_freq = __expf(-(float)d * (11.512925465f / 64.0f));
                float sn, cs;
                sincosf(pos * inv_freq, &sn, &cs);
                const float x1 = qv[p * 8 + j];            // d
                const float x2 = qv[(p + 2) * 8 + j];      // d+64
                qv[p * 8 + j]       = x1 * cs - x2 * sn;
                qv[(p + 2) * 8 + j] = x2 * cs + x1 * sn;
            }
        #pragma unroll
        for (int ks = 0; ks < 4; ++ks)
            #pragma unroll
            for (int j = 0; j < 8; ++j)
                qf[ks][j] = (_Float16)(qv[ks * 8 + j] * scale);
    }

    f32x4 o[8];
    #pragma unroll
    for (int c = 0; c < 8; ++c)
        #pragma unroll
        for (int r = 0; r < 4; ++r) o[c][r] = 0.0f;
    float mrun[4], lrun[4];
    #pragma unroll
    for (int r = 0; r < 4; ++r) { mrun[r] = NEG_BIG; lrun[r] = 0.0f; }

    int s_lo = q0 - window + 1;
    if (s_lo < 0) s_lo = 0;
    s_lo &= ~(BS - 1);
    const int tile0  = s_lo >> 5;
    const int ntiles = ((q0 + BQ) - s_lo) >> 5;

    const _Float16* gK = Kt + ((size_t)kvh * NTILE) * 4096;
    const _Float16* gV = Vt + ((size_t)kvh * NTILE) * 4096;

    _Float16* Psw = &Ps[wave][0];

    // per-wave stage of one tile's two 8KB images (2 x 1KB chunks each)
    auto STAGE = [&](int buf, int tile) {
        const size_t toff = (size_t)tile * 4096;
        #pragma unroll
        for (int i = 0; i < 2; ++i) {
            const int off = (wave * 2 + i) * 512;        // halves
            gload_lds16(gK + toff + off + lane * 8, &KS[buf][off]);
            gload_lds16(gV + toff + off + lane * 8, &VS[buf][off]);
        }
    };

    STAGE(0, tile0);
    __syncthreads();                       // drains vmcnt -> buf0 ready
    int cur = 0;

    for (int it = 0; it < ntiles; ++it) {
        const int st = s_lo + it * BS;
        if (it + 1 < ntiles) STAGE(cur ^ 1, tile0 + it + 1);   // prefetch

        // ---- S = Q K^T  (two 16x16 subtiles over s), log2-units
        f32x4 acc0, acc1;
        #pragma unroll
        for (int r = 0; r < 4; ++r) { acc0[r] = 0.0f; acc1[r] = 0.0f; }
        #pragma unroll
        for (int ks = 0; ks < 4; ++ks) {
            const int g = (ks * 4 + quad) * 256;         // granule gd = d/8
            const f16x8 b0 = *(const f16x8*)&KS[cur][g + l15 * 8];
            const f16x8 b1 = *(const f16x8*)&KS[cur][g + (16 + l15) * 8];
            acc0 = __builtin_amdgcn_mfma_f32_16x16x32_f16(qf[ks], b0, acc0, 0, 0, 0);
            acc1 = __builtin_amdgcn_mfma_f32_16x16x32_f16(qf[ks], b1, acc1, 0, 0, 0);
        }

        // ---- mask + online softmax (exp2 domain, defer-max THR=8)
        const int qb  = q0 + wave * 16 + quad * 4;
        const int s0g = st + l15;
        const int s1g = st + 16 + l15;
        #pragma unroll
        for (int r = 0; r < 4; ++r) {
            const int q = qb + r;
            const bool v0 = (s0g <= q) && (s0g > q - window);
            const bool v1 = (s1g <= q) && (s1g > q - window);
            float a = v0 ? acc0[r] : NEG_BIG;
            float b = v1 ? acc1[r] : NEG_BIG;
            float mx = fmaxf(a, b);
            mx = fmaxf(mx, __shfl_xor(mx, 1));
            mx = fmaxf(mx, __shfl_xor(mx, 2));
            mx = fmaxf(mx, __shfl_xor(mx, 4));
            mx = fmaxf(mx, __shfl_xor(mx, 8));
            if (__any(mx > mrun[r] + 8.0f)) {            // wave-uniform
                const float mnew  = fmaxf(mrun[r], mx);
                const float alpha = __builtin_amdgcn_exp2f(mrun[r] - mnew);
                mrun[r] = mnew;
                lrun[r] *= alpha;
                #pragma unroll
                for (int c = 0; c < 8; ++c) o[c][r] *= alpha;
            }
            const float e0 = v0 ? __builtin_amdgcn_exp2f(acc0[r] - mrun[r]) : 0.0f;
            const float e1 = v1 ? __builtin_amdgcn_exp2f(acc1[r] - mrun[r]) : 0.0f;
            const _Float16 p0 = (_Float16)e0;
            const _Float16 p1 = (_Float16)e1;
            Psw[(quad * 4 + r) * PSTR + l15]      = p0;
            Psw[(quad * 4 + r) * PSTR + 16 + l15] = p1;
            float sum = (float)p0 + (float)p1;
            sum += __shfl_xor(sum, 1);
            sum += __shfl_xor(sum, 2);
            sum += __shfl_xor(sum, 4);
            sum += __shfl_xor(sum, 8);
            lrun[r] += sum;
        }

        // ---- PV: A = P (A-layout from per-wave LDS), B = V image rows
        const f16x8 pa = *(const f16x8*)&Psw[l15 * PSTR + quad * 8];
        #pragma unroll
        for (int c = 0; c < 8; ++c) {
            const f16x8 vb = *(const f16x8*)&VS[cur][quad * 1024 + (16 * c + l15) * 8];
            o[c] = __builtin_amdgcn_mfma_f32_16x16x32_f16(pa, vb, o[c], 0, 0, 0);
        }

        __syncthreads();    // drains vmcnt (prefetch landed) + buf reuse fence
        cur ^= 1;
    }

    // ---- epilogue: normalize, write bf16 out[q][h*128 + d]
    #pragma unroll
    for (int r = 0; r < 4; ++r) {
        const float inv = 1.0f / lrun[r];   // diagonal always valid
        __hip_bfloat16* op = out
                  + (size_t)(q0 + wave * 16 + quad * 4 + r) * (NHEAD * HEADDIM)
                  + h * HEADDIM + l15;
        #pragma unroll
        for (int c = 0; c < 8; ++c) op[16 * c] = __float2bfloat16(o[c][r] * inv);
    }
}

// ---------------------------------------------------------------------------
extern "C" void kernel_launch(void* const* d_in, const int* in_sizes, int n_in,
                              void* d_out, int out_size, void* d_ws, size_t ws_size,
                              hipStream_t stream)
{
    const int*   positions = (const int*)d_in[0];
    const float* hidden    = (const float*)d_in[1];
    const float* wqkv      = (const float*)d_in[2];
    const float* bqkv      = (const float*)d_in[3];
    const float* wo        = (const float*)d_in[4];
    const float* bo        = (const float*)d_in[5];
    const int*   windowp   = (const int*)d_in[6];
    float* outp = (float*)d_out;

    // ws layout:
    //   qkv   fp32 [T,5632]      46.1 MB
    //   hbf   bf16 [T,4608]      18.9 MB
    //   wqbf  bf16 [5632,4608]   51.9 MB
    //   wobf  bf16 [4608,4608]   42.5 MB
    //   abf   bf16 [T,4608]      18.9 MB
    //   Kt/Vt f16 tile images    2 x 2.0 MB
    float* qkv = (float*)d_ws;
    __hip_bfloat16* hbf  = (__hip_bfloat16*)(qkv + (size_t)T_SEQ * NQKV);
    __hip_bfloat16* wqbf = hbf  + (size_t)T_SEQ * HIDDEN;
    __hip_bfloat16* wobf = wqbf + (size_t)NQKV * HIDDEN;
    __hip_bfloat16* abf  = wobf + (size_t)HIDDEN * HIDDEN;
    _Float16*       Kt   = (_Float16*)(abf + (size_t)T_SEQ * HIDDEN);
    _Float16*       Vt   = Kt + (size_t)NKVH * NTILE * 4096;

    cvt_bf16_kernel<<<1024, 256, 0, stream>>>(hidden, hbf, T_SEQ * HIDDEN / 8);
    cvt_bf16_kernel<<<2048, 256, 0, stream>>>(wqkv, wqbf, NQKV * HIDDEN / 8);
    cvt_bf16_kernel<<<2048, 256, 0, stream>>>(wo, wobf, HIDDEN * HIDDEN / 8);

    gemm_bf16bt_kernel<<<dim3(NQKV / 128, T_SEQ / 128), 256, 0, stream>>>(
        hbf, wqbf, bqkv, qkv, NQKV, HIDDEN);

    prep_kv_kernel<<<dim3(NTILE, NKVH), 256, 0, stream>>>(
        positions, qkv, Kt, Vt);

    attn_kernel<<<dim3(NHEAD, T_SEQ / BQ), 256, 0, stream>>>(
        qkv, positions, Kt, Vt, abf, windowp);

    gemm_bf16bt_kernel<<<dim3(HIDDEN / 128, T_SEQ / 128), 256, 0, stream>>>(
        abf, wobf, bo, outp, HIDDEN, HIDDEN);
}

// Round 6
// 576.826 us; speedup vs baseline: 1.3698x; 1.0875x over previous
//
#include <hip/hip_runtime.h>
#include <hip/hip_bf16.h>
#include <math.h>

// Starcoder2 attention R9:
//  - attn: SWAPPED-OPERAND QK^T (S^T = mfma(K,Q)) and PV (O^T = mfma(Vt,Pt)).
//    MFMA A/B frags share the same lane mapping, so all LDS reads and the Q
//    register frags are unchanged -- only operand order flips. Each thread
//    now owns ONE q-column's 8 S-values: softmax row-reduce = in-lane tree +
//    2 shuffles (xor16/32) instead of 4 rows x 8 shuffles (32 -> 4 shfl/tile);
//    mrun/lrun become scalars. Sentinel masking (-2e9 vs mrun init -1e9)
//    makes exp2 underflow to exact 0 for masked entries (no post-exp selects;
//    all-masked-tile edges audited). P^T written as 2x8B stores; epilogue
//    8x8B stores.
//  - GEMM/prep_kv/cvt: unchanged from R8b (verified 627 us, absmax 0.03125).
// T=2048, HID=4608, H=36, KV=4, D=128, window=1024.

#define T_SEQ   2048
#define HIDDEN  4608
#define NHEAD   36
#define NKVH    4
#define HEADDIM 128
#define GQA_G   9
#define NQKV    5632
#define KOFF    4608
#define VOFF    5120
#define NEG_BIG -1e30f
#define BQ 64
#define BS 32
#define NTILE   64            // T_SEQ / BS
#define PSTR 40

typedef short    bf16x8 __attribute__((ext_vector_type(8)));
typedef _Float16 f16x8  __attribute__((ext_vector_type(8)));
typedef _Float16 f16x4  __attribute__((ext_vector_type(4)));
typedef float    f32x4  __attribute__((ext_vector_type(4)));

// pack 8 fp32 -> 8 bf16 (RNE)
__device__ inline bf16x8 pack8(float4 u, float4 v) {
    union { bf16x8 v8; __hip_bfloat162 h[4]; } r;
    r.h[0] = __float22bfloat162_rn(make_float2(u.x, u.y));
    r.h[1] = __float22bfloat162_rn(make_float2(u.z, u.w));
    r.h[2] = __float22bfloat162_rn(make_float2(v.x, v.y));
    r.h[3] = __float22bfloat162_rn(make_float2(v.z, v.w));
    return r.v8;
}

// async global->LDS, 16 B per lane. LDS dest wave-uniform; lane l lands at
// ldsbase + l*16; global source address is per-lane.
typedef const __attribute__((address_space(1))) int* gas_ptr;
typedef __attribute__((address_space(3))) int*       las_ptr;
__device__ __forceinline__ void gload_lds16(const void* g, void* l) {
    __builtin_amdgcn_global_load_lds((gas_ptr)g, (las_ptr)l, 16, 0, 0);
}

// ---------------------------------------------------------------------------
// fp32 -> bf16 conversion (memory-bound, vectorized 8 elems/thread/iter)
// ---------------------------------------------------------------------------
__global__ __launch_bounds__(256)
void cvt_bf16_kernel(const float* __restrict__ in, __hip_bfloat16* __restrict__ out,
                     int n8)
{
    for (int i = blockIdx.x * 256 + threadIdx.x; i < n8; i += gridDim.x * 256) {
        const float4 a = *(const float4*)(in + (size_t)i * 8);
        const float4 b = *(const float4*)(in + (size_t)i * 8 + 4);
        *(bf16x8*)(out + (size_t)i * 8) = pack8(a, b);
    }
}

// ---------------------------------------------------------------------------
// GEMM: C[M,N](fp32) = A[M,K](bf16) @ B[N,K](bf16)^T + bias
// 128x128 tile, BK=32, 4 waves, global_load_lds staging, double-buffered
// 2-phase: STAGE(next) || compute(cur), one vmcnt(0)+barrier per K-step.
// ---------------------------------------------------------------------------
__global__ __launch_bounds__(256)
void gemm_bf16bt_kernel(const __hip_bfloat16* __restrict__ A,
                        const __hip_bfloat16* __restrict__ B,
                        const float* __restrict__ bias,
                        float* __restrict__ C, int N, int K)
{
    __shared__ short As[2][128 * 32];   // 8 KB each, row-major [row][k]
    __shared__ short Bs[2][128 * 32];

    const int tid  = threadIdx.x;
    const int lane = tid & 63;
    const int wave = tid >> 6;
    const int row0 = blockIdx.y * 128;
    const int col0 = blockIdx.x * 128;
    const int wr   = (wave >> 1) * 64;
    const int wc   = (wave & 1) * 64;
    const int fr   = lane & 15;
    const int fk   = (lane >> 4) * 8;

    // staging: 1 KB chunk = 16 rows x 64 B; lane l -> row +(l>>2), col (l&3)*8
    const int srow = lane >> 2;
    const int scol = (lane & 3) * 8;

    const __hip_bfloat16* Ag0 = A + (size_t)(row0 + wave * 32 + srow) * K + scol;
    const __hip_bfloat16* Ag1 = Ag0 + (size_t)16 * K;
    const __hip_bfloat16* Bg0 = B + (size_t)(col0 + wave * 32 + srow) * K + scol;
    const __hip_bfloat16* Bg1 = Bg0 + (size_t)16 * K;

    short* Al0[2] = { &As[0][(wave * 32) * 32],      &As[1][(wave * 32) * 32] };
    short* Al1[2] = { &As[0][(wave * 32 + 16) * 32], &As[1][(wave * 32 + 16) * 32] };
    short* Bl0[2] = { &Bs[0][(wave * 32) * 32],      &Bs[1][(wave * 32) * 32] };
    short* Bl1[2] = { &Bs[0][(wave * 32 + 16) * 32], &Bs[1][(wave * 32 + 16) * 32] };

    f32x4 acc[4][4];
    #pragma unroll
    for (int i = 0; i < 4; ++i)
        #pragma unroll
        for (int j = 0; j < 4; ++j)
            #pragma unroll
            for (int r = 0; r < 4; ++r) acc[i][j][r] = 0.0f;

    // prologue: stage tile 0 into buf 0
    gload_lds16(Ag0, Al0[0]);
    gload_lds16(Ag1, Al1[0]);
    gload_lds16(Bg0, Bl0[0]);
    gload_lds16(Bg1, Bl1[0]);
    __syncthreads();                       // drains vmcnt -> buf0 ready
    int cur = 0;

    for (int k0 = 0; k0 < K; k0 += 32) {
        if (k0 + 32 < K) {                 // prefetch next K-tile
            const int kn = k0 + 32;
            const int nb = cur ^ 1;
            gload_lds16(Ag0 + kn, Al0[nb]);
            gload_lds16(Ag1 + kn, Al1[nb]);
            gload_lds16(Bg0 + kn, Bl0[nb]);
            gload_lds16(Bg1 + kn, Bl1[nb]);
        }

        bf16x8 af[4], bfr[4];
        #pragma unroll
        for (int i = 0; i < 4; ++i)
            af[i] = *(const bf16x8*)&As[cur][(wr + i * 16 + fr) * 32 + fk];
        #pragma unroll
        for (int j = 0; j < 4; ++j)
            bfr[j] = *(const bf16x8*)&Bs[cur][(wc + j * 16 + fr) * 32 + fk];

        #pragma unroll
        for (int i = 0; i < 4; ++i)
            #pragma unroll
            for (int j = 0; j < 4; ++j)
                acc[i][j] = __builtin_amdgcn_mfma_f32_16x16x32_bf16(
                    af[i], bfr[j], acc[i][j], 0, 0, 0);

        __syncthreads();   // prefetch landed (vmcnt0) + cur-buf reads done
        cur ^= 1;
    }

    const int quad = lane >> 4;
    #pragma unroll
    for (int j = 0; j < 4; ++j) {
        const int col = col0 + wc + j * 16 + fr;
        const float bv = bias[col];
        #pragma unroll
        for (int i = 0; i < 4; ++i) {
            const int rowb = row0 + wr + i * 16 + quad * 4;
            #pragma unroll
            for (int r = 0; r < 4; ++r)
                C[(size_t)(rowb + r) * N + col] = acc[i][j][r] + bv;
        }
    }
}

// ---------------------------------------------------------------------------
// prep_kv: per (tile, kvh) build two 8KB f16 LDS images:
//   K image [gd=d/8][s][j]: RoPE'd K, f16      (gd 0..15, s 0..31, j=d%8)
//   V image [q=s/8][d][j] : V transposed, f16  (q 0..3, d 0..127, j=s%8)
// grid (NTILE, NKVH) x 256 threads.
// ---------------------------------------------------------------------------
__global__ __launch_bounds__(256)
void prep_kv_kernel(const int* __restrict__ positions,
                    const float* __restrict__ qkv,
                    _Float16* __restrict__ Kt,
                    _Float16* __restrict__ Vt)
{
    const int tile = blockIdx.x;
    const int kvh  = blockIdx.y;
    const int t    = threadIdx.x;
    const size_t ib = ((size_t)kvh * NTILE + tile) * 4096;

    // ---- K: thread -> row s = t>>3, d-halfpair base j8 = (t&7)*8
    {
        const int s   = t >> 3;
        const int j8  = (t & 7) * 8;
        const int row = tile * BS + s;
        const float* kp = qkv + (size_t)row * NQKV + KOFF + kvh * HEADDIM;
        float x1[8], x2[8];
        *(float4*)&x1[0] = *(const float4*)(kp + j8);
        *(float4*)&x1[4] = *(const float4*)(kp + j8 + 4);
        *(float4*)&x2[0] = *(const float4*)(kp + 64 + j8);
        *(float4*)&x2[4] = *(const float4*)(kp + 64 + j8 + 4);
        const float pos = (float)positions[row];
        f16x8 H1, H2;
        #pragma unroll
        for (int j = 0; j < 8; ++j) {
            const int d = j8 + j;
            const float inv_freq = __expf(-(float)d * (11.512925465f / 64.0f));
            float sn, cs;
            sincosf(pos * inv_freq, &sn, &cs);
            H1[j] = (_Float16)(x1[j] * cs - x2[j] * sn);
            H2[j] = (_Float16)(x2[j] * cs + x1[j] * sn);
        }
        const int gd1 = (t & 7);       // d in [0,64)
        const int gd2 = gd1 + 8;       // d+64
        *(f16x8*)&Kt[ib + gd1 * 256 + s * 8] = H1;
        *(f16x8*)&Kt[ib + gd2 * 256 + s * 8] = H2;
    }

    // ---- V: thread -> q = t>>6, d-pair d0 = (t&63)*2
    {
        const int q  = t >> 6;
        const int d0 = (t & 63) * 2;
        const float* vp = qkv + (size_t)(tile * BS + q * 8) * NQKV + VOFF
                        + kvh * HEADDIM + d0;
        f16x8 V0, V1;
        #pragma unroll
        for (int j = 0; j < 8; ++j) {
            const float2 vv = *(const float2*)(vp + (size_t)j * NQKV);
            V0[j] = (_Float16)vv.x;
            V1[j] = (_Float16)vv.y;
        }
        *(f16x8*)&Vt[ib + q * 1024 + d0 * 8]       = V0;
        *(f16x8*)&Vt[ib + q * 1024 + (d0 + 1) * 8] = V1;
    }
}

// ---------------------------------------------------------------------------
// MFMA flash attention (windowed causal GQA), R9: swapped-operand layout.
// S^T = mfma(K,Q): thread owns column q=l15, rows s = quad*4+r (+16).
// Softmax: in-lane tree + 2 shuffles; scalar mrun/lrun; sentinel masking.
// PV: O^T = mfma(Vt, Pt): o[c][r] = O[q=l15][d=16c+quad*4+r].
// ---------------------------------------------------------------------------
__global__ __launch_bounds__(256)
void attn_kernel(const float* __restrict__ qkv,
                 const int* __restrict__ positions,
                 const _Float16* __restrict__ Kt,
                 const _Float16* __restrict__ Vt,
                 __hip_bfloat16* __restrict__ out,
                 const int* __restrict__ windowp)
{
    __shared__ _Float16 KS[2][4096];                // 16 KB
    __shared__ _Float16 VS[2][4096];                // 16 KB
    __shared__ _Float16 Ps[4][16 * PSTR];           // 5 KB   (total 37888 B)

    const int h    = blockIdx.x;
    const int q0   = (T_SEQ / BQ - 1 - blockIdx.y) * BQ;   // heavy blocks first
    const int kvh  = h / GQA_G;
    const int tid  = threadIdx.x;
    const int lane = tid & 63;
    const int wave = tid >> 6;
    const int l15  = lane & 15;
    const int quad = lane >> 4;
    const int window = *windowp;
    // 1/sqrt(128) * log2(e): softmax done in exp2 domain
    const float scale = 0.088388347648318447f * 1.4426950408889634f;

    // ---- Q load + in-register RoPE + scale + f16 frags (B operand; lane
    //      holds Q[q=l15][d=ks*32+quad*8+j])
    f16x8 qf[4];
    const int q_g = q0 + wave * 16 + l15;      // this thread's q column
    {
        const float* qp = qkv + (size_t)q_g * NQKV + h * HEADDIM + quad * 8;
        float qv[32];                         // [ks*8+j] = Q[d = ks*32+quad*8+j]
        #pragma unroll
        for (int ks = 0; ks < 4; ++ks) {
            *(float4*)&qv[ks * 8]     = *(const float4*)(qp + ks * 32);
            *(float4*)&qv[ks * 8 + 4] = *(const float4*)(qp + ks * 32 + 4);
        }
        const float pos = (float)positions[q_g];
        #pragma unroll
        for (int p = 0; p < 2; ++p)
            #pragma unroll
            for (int j = 0; j < 8; ++j) {
                const int d = p * 32 + quad * 8 + j;       // < 64
                const float inv_freq = __expf(-(float)d * (11.512925465f / 64.0f));
                float sn, cs;
                sincosf(pos * inv_freq, &sn, &cs);
                const float x1 = qv[p * 8 + j];            // d
                const float x2 = qv[(p + 2) * 8 + j];      // d+64
                qv[p * 8 + j]       = x1 * cs - x2 * sn;
                qv[(p + 2) * 8 + j] = x2 * cs + x1 * sn;
            }
        #pragma unroll
        for (int ks = 0; ks < 4; ++ks)
            #pragma unroll
            for (int j = 0; j < 8; ++j)
                qf[ks][j] = (_Float16)(qv[ks * 8 + j] * scale);
    }

    f32x4 o[8];                               // o[c][r] = O[q=l15][16c+quad*4+r]
    #pragma unroll
    for (int c = 0; c < 8; ++c)
        #pragma unroll
        for (int r = 0; r < 4; ++r) o[c][r] = 0.0f;
    float mrun = -1e9f;                       // sentinel: masked sv = -2e9
    float lrun = 0.0f;

    int s_lo = q0 - window + 1;
    if (s_lo < 0) s_lo = 0;
    s_lo &= ~(BS - 1);
    const int tile0  = s_lo >> 5;
    const int ntiles = ((q0 + BQ) - s_lo) >> 5;

    const _Float16* gK = Kt + ((size_t)kvh * NTILE) * 4096;
    const _Float16* gV = Vt + ((size_t)kvh * NTILE) * 4096;

    _Float16* Psw = &Ps[wave][0];             // Pt[q=l15][s], stride PSTR

    // per-wave stage of one tile's two 8KB images (2 x 1KB chunks each)
    auto STAGE = [&](int buf, int tile) {
        const size_t toff = (size_t)tile * 4096;
        #pragma unroll
        for (int i = 0; i < 2; ++i) {
            const int off = (wave * 2 + i) * 512;        // halves
            gload_lds16(gK + toff + off + lane * 8, &KS[buf][off]);
            gload_lds16(gV + toff + off + lane * 8, &VS[buf][off]);
        }
    };

    STAGE(0, tile0);
    __syncthreads();                       // drains vmcnt -> buf0 ready
    int cur = 0;

    for (int it = 0; it < ntiles; ++it) {
        const int st = s_lo + it * BS;
        if (it + 1 < ntiles) STAGE(cur ^ 1, tile0 + it + 1);   // prefetch

        // ---- S^T = mfma(K, Q): C row = s_local (quad*4+r), col = q (l15)
        f32x4 acc0, acc1;
        #pragma unroll
        for (int r = 0; r < 4; ++r) { acc0[r] = 0.0f; acc1[r] = 0.0f; }
        #pragma unroll
        for (int ks = 0; ks < 4; ++ks) {
            const int g = (ks * 4 + quad) * 256;         // granule gd = d/8
            const f16x8 b0 = *(const f16x8*)&KS[cur][g + l15 * 8];
            const f16x8 b1 = *(const f16x8*)&KS[cur][g + (16 + l15) * 8];
            acc0 = __builtin_amdgcn_mfma_f32_16x16x32_f16(b0, qf[ks], acc0, 0, 0, 0);
            acc1 = __builtin_amdgcn_mfma_f32_16x16x32_f16(b1, qf[ks], acc1, 0, 0, 0);
        }

        // ---- softmax on thread-local column (8 s-values), defer-max THR=8
        const int dq = q_g - st;                  // q - st
        float sv[8];
        #pragma unroll
        for (int r = 0; r < 4; ++r) {
            const int o0 = quad * 4 + r;
            const bool v0 = (unsigned)(dq - o0)      < (unsigned)window;
            const bool v1 = (unsigned)(dq - o0 - 16) < (unsigned)window;
            sv[r]     = v0 ? acc0[r] : -2e9f;
            sv[4 + r] = v1 ? acc1[r] : -2e9f;
        }
        float mx = sv[0];
        #pragma unroll
        for (int i = 1; i < 8; ++i) mx = fmaxf(mx, sv[i]);
        mx = fmaxf(mx, __shfl_xor(mx, 16));
        mx = fmaxf(mx, __shfl_xor(mx, 32));
        if (__any(mx > mrun + 8.0f)) {            // wave-uniform rescale
            const float mnew  = fmaxf(mrun, mx);
            const float alpha = __builtin_amdgcn_exp2f(mrun - mnew);
            mrun = mnew;
            lrun *= alpha;
            #pragma unroll
            for (int c = 0; c < 8; ++c)
                #pragma unroll
                for (int r = 0; r < 4; ++r) o[c][r] *= alpha;
        }
        float e[8];
        float sum = 0.0f;
        #pragma unroll
        for (int i = 0; i < 8; ++i) {             // masked: exp2(~-2e9) = 0
            e[i] = __builtin_amdgcn_exp2f(sv[i] - mrun);
            sum += e[i];
        }
        sum += __shfl_xor(sum, 16);
        sum += __shfl_xor(sum, 32);
        lrun += sum;

        // ---- P^T -> per-wave LDS: Pt[q=l15][s]; two 8B stores
        f16x4 pl, ph;
        #pragma unroll
        for (int r = 0; r < 4; ++r) { pl[r] = (_Float16)e[r]; ph[r] = (_Float16)e[4 + r]; }
        *(f16x4*)&Psw[l15 * PSTR + quad * 4]      = pl;    // s = quad*4+r
        *(f16x4*)&Psw[l15 * PSTR + 16 + quad * 4] = ph;    // s = 16+quad*4+r
        // B-frag: Pt[q=l15][s=quad*8+j]
        const f16x8 pa = *(const f16x8*)&Psw[l15 * PSTR + quad * 8];

        // ---- PV: O^T = mfma(Vt, Pt); vb = V[s=quad*8+j][d=16c+l15]
        #pragma unroll
        for (int c = 0; c < 8; ++c) {
            const f16x8 vb = *(const f16x8*)&VS[cur][quad * 1024 + (16 * c + l15) * 8];
            o[c] = __builtin_amdgcn_mfma_f32_16x16x32_f16(vb, pa, o[c], 0, 0, 0);
        }

        __syncthreads();    // drains vmcnt (prefetch landed) + buf reuse fence
        cur ^= 1;
    }

    // ---- epilogue: normalize, write bf16 out[q][h*128 + d], 8B stores
    {
        const float inv = 1.0f / lrun;            // diagonal always valid
        __hip_bfloat16* op = out + (size_t)q_g * (NHEAD * HEADDIM)
                           + h * HEADDIM + quad * 4;
        #pragma unroll
        for (int c = 0; c < 8; ++c) {
            union { ushort4 u; __hip_bfloat16 x[4]; } w;
            #pragma unroll
            for (int r = 0; r < 4; ++r) w.x[r] = __float2bfloat16(o[c][r] * inv);
            *(ushort4*)&op[16 * c] = w.u;         // d = 16c + quad*4 + r
        }
    }
}

// ---------------------------------------------------------------------------
extern "C" void kernel_launch(void* const* d_in, const int* in_sizes, int n_in,
                              void* d_out, int out_size, void* d_ws, size_t ws_size,
                              hipStream_t stream)
{
    const int*   positions = (const int*)d_in[0];
    const float* hidden    = (const float*)d_in[1];
    const float* wqkv      = (const float*)d_in[2];
    const float* bqkv      = (const float*)d_in[3];
    const float* wo        = (const float*)d_in[4];
    const float* bo        = (const float*)d_in[5];
    const int*   windowp   = (const int*)d_in[6];
    float* outp = (float*)d_out;

    // ws layout:
    //   qkv   fp32 [T,5632]      46.1 MB
    //   hbf   bf16 [T,4608]      18.9 MB
    //   wqbf  bf16 [5632,4608]   51.9 MB
    //   wobf  bf16 [4608,4608]   42.5 MB
    //   abf   bf16 [T,4608]      18.9 MB
    //   Kt/Vt f16 tile images    2 x 2.0 MB
    float* qkv = (float*)d_ws;
    __hip_bfloat16* hbf  = (__hip_bfloat16*)(qkv + (size_t)T_SEQ * NQKV);
    __hip_bfloat16* wqbf = hbf  + (size_t)T_SEQ * HIDDEN;
    __hip_bfloat16* wobf = wqbf + (size_t)NQKV * HIDDEN;
    __hip_bfloat16* abf  = wobf + (size_t)HIDDEN * HIDDEN;
    _Float16*       Kt   = (_Float16*)(abf + (size_t)T_SEQ * HIDDEN);
    _Float16*       Vt   = Kt + (size_t)NKVH * NTILE * 4096;

    cvt_bf16_kernel<<<1024, 256, 0, stream>>>(hidden, hbf, T_SEQ * HIDDEN / 8);
    cvt_bf16_kernel<<<2048, 256, 0, stream>>>(wqkv, wqbf, NQKV * HIDDEN / 8);
    cvt_bf16_kernel<<<2048, 256, 0, stream>>>(wo, wobf, HIDDEN * HIDDEN / 8);

    gemm_bf16bt_kernel<<<dim3(NQKV / 128, T_SEQ / 128), 256, 0, stream>>>(
        hbf, wqbf, bqkv, qkv, NQKV, HIDDEN);

    prep_kv_kernel<<<dim3(NTILE, NKVH), 256, 0, stream>>>(
        positions, qkv, Kt, Vt);

    attn_kernel<<<dim3(NHEAD, T_SEQ / BQ), 256, 0, stream>>>(
        qkv, positions, Kt, Vt, abf, windowp);

    gemm_bf16bt_kernel<<<dim3(HIDDEN / 128, T_SEQ / 128), 256, 0, stream>>>(
        abf, wobf, bo, outp, HIDDEN, HIDDEN);
}